// Round 8
// baseline (175.422 us; speedup 1.0000x reference)
//
#include <hip/hip_runtime.h>
#include <hip/hip_bf16.h>
#include <stdint.h>

// Problem constants
#define BB 4
#define NN 2048
#define DIMD 512
#define HH 8
#define DKK 64
#define MTOT (BB * NN)          // 8192
constexpr float SCALE = 0.125f; // DK^-0.5

typedef __attribute__((ext_vector_type(4))) float f32x4;
typedef __attribute__((ext_vector_type(2))) float f32x2;
typedef __attribute__((ext_vector_type(8))) short bf16x8;   // 8 bf16 (4 VGPRs)
typedef __attribute__((ext_vector_type(4))) _Float16 f16x4; // 4 f16 (2 VGPRs)
typedef __attribute__((ext_vector_type(2))) __fp16 fp16v2;  // cvt_pkrtz result
typedef __attribute__((ext_vector_type(4))) __fp16 fp16v4;
typedef __attribute__((ext_vector_type(2))) unsigned int u32x2;

union pack8 { unsigned short s[8]; uint4 v; };
union fragu { u32x2 h[2]; bf16x8 v; };

__device__ __forceinline__ unsigned short f2bf(float f) {
  union { float f; uint32_t u; } v; v.f = f;
  uint32_t u = v.u;
  return (unsigned short)((u + 0x7FFFu + ((u >> 16) & 1u)) >> 16); // RNE
}

__device__ __forceinline__ unsigned short f2h(float f) {
  union { _Float16 h; unsigned short u; } c; c.h = (_Float16)f;
  return c.u;
}

// LDS helpers for stride-68 (8B-aligned) rows: explicit b64 ops
__device__ __forceinline__ bf16x8 ld_frag(const unsigned short* p) {
  fragu f;
  f.h[0] = *(const u32x2*)p;
  f.h[1] = *(const u32x2*)(p + 4);
  return f.v;
}
__device__ __forceinline__ void st8(unsigned short* p, uint4 v) {
  *(u32x2*)p = (u32x2){v.x, v.y};
  *(u32x2*)(p + 4) = (u32x2){v.z, v.w};
}

// sigmoid via e=exp(-|x|) (1 transcendental) + deg-3 minimax for 1/(1+e)-0.5
__device__ __forceinline__ f16x4 sig_pack(f32x4 sv) {
  float e0 = __expf(-__builtin_fabsf(sv[0]));
  float e1 = __expf(-__builtin_fabsf(sv[1]));
  float e2 = __expf(-__builtin_fabsf(sv[2]));
  float e3 = __expf(-__builtin_fabsf(sv[3]));
  const f32x2 c3 = {-0.22184f, -0.22184f};
  const f32x2 c2 = {0.66550f, 0.66550f};
  const f32x2 c1 = {-0.94280f, -0.94280f};
  const f32x2 c0 = {0.49826f, 0.49826f};
  f32x2 eA = {e0, e1}, eB = {e2, e3};
  f32x2 pA = __builtin_elementwise_fma(
      __builtin_elementwise_fma(__builtin_elementwise_fma(c3, eA, c2), eA, c1),
      eA, c0);
  f32x2 pB = __builtin_elementwise_fma(
      __builtin_elementwise_fma(__builtin_elementwise_fma(c3, eB, c2), eB, c1),
      eB, c0);
  float r0 = __builtin_copysignf(pA.x, sv[0]) + 0.5f;
  float r1 = __builtin_copysignf(pA.y, sv[1]) + 0.5f;
  float r2 = __builtin_copysignf(pB.x, sv[2]) + 0.5f;
  float r3 = __builtin_copysignf(pB.y, sv[3]) + 0.5f;
  fp16v2 lo = __builtin_amdgcn_cvt_pkrtz(r0, r1);
  fp16v2 hi = __builtin_amdgcn_cvt_pkrtz(r2, r3);
  fp16v4 p;
  p.x = lo.x; p.y = lo.y; p.z = hi.x; p.w = hi.y;
  return __builtin_bit_cast(f16x4, p);
}

// ---------------------------------------------------------------------------
// prep (fused):
//   blocks [0,2048):    xb bf16 [B*N][DIM] — streaming convert
//   blocks [2048,2304): xtf f16 [B][DIM][N] — thread = (d, 64 n) -> one 128B
//                       contiguous write (full-line), reads coalesced over d
//   blocks [2304,2432): Wq/Wk -> Wt bf16 [N][K] via stride-68 LDS tile
// ---------------------------------------------------------------------------
__global__ __launch_bounds__(256) void prep(const float* __restrict__ x,
                                            const float* __restrict__ wq,
                                            const float* __restrict__ wk,
                                            unsigned short* __restrict__ xb,
                                            unsigned short* __restrict__ xtf,
                                            unsigned short* __restrict__ wtq,
                                            unsigned short* __restrict__ wtk) {
  const int bx = blockIdx.x, tid = threadIdx.x;
  if (bx < 2048) {
    size_t base = ((size_t)bx * 256 + tid) * 8;
    float4 a = *(const float4*)(x + base);
    float4 b = *(const float4*)(x + base + 4);
    pack8 p;
    p.s[0] = f2bf(a.x); p.s[1] = f2bf(a.y); p.s[2] = f2bf(a.z); p.s[3] = f2bf(a.w);
    p.s[4] = f2bf(b.x); p.s[5] = f2bf(b.y); p.s[6] = f2bf(b.z); p.s[7] = f2bf(b.w);
    *(uint4*)(xb + base) = p.v;
  } else if (bx < 2304) {
    // xtf: 256 blocks: b(4) x dt(8) x nt(8); thread: d = dt*64+(tid&63),
    // n-run = nt*256 + (tid>>6)*64 .. +64 -> 128B contiguous store
    int q = bx - 2048;
    int b = q >> 6, r = q & 63;
    int dt = r >> 3, nt = r & 7;
    int d = dt * 64 + (tid & 63);
    int n0 = nt * 256 + (tid >> 6) * 64;
    const float* xp = x + ((size_t)b * NN + n0) * DIMD + d;
    unsigned short* dp = xtf + ((size_t)b * DIMD + d) * NN + n0;
#pragma unroll
    for (int g = 0; g < 8; g++) {
      pack8 pa;
#pragma unroll
      for (int k = 0; k < 8; k++) pa.s[k] = f2h(xp[(size_t)(g * 8 + k) * DIMD]);
      *(uint4*)(dp + g * 8) = pa.v;
    }
  } else {
    __shared__ __align__(16) unsigned short T[64][68];
    int q = bx - 2304;
    const float* w = (q >= 64) ? wk : wq;
    unsigned short* wt = (q >= 64) ? wtk : wtq;
    int r = q & 63;
    int kt = r >> 3, nt = r & 7;
    const int k0 = kt * 64, n0 = nt * 64;
#pragma unroll
    for (int rr = 0; rr < 16; rr++) {
      int idx = tid + rr * 256;
      int kl = idx >> 6, nl = idx & 63;
      T[nl][kl] = f2bf(w[(size_t)(k0 + kl) * DIMD + n0 + nl]);
    }
    __syncthreads();
#pragma unroll
    for (int rr = 0; rr < 2; rr++) {
      int idx = tid + rr * 256;
      int nl = idx >> 3, c = idx & 7;
      fragu f;
      f.h[0] = *(const u32x2*)&T[nl][c * 8];
      f.h[1] = *(const u32x2*)&T[nl][c * 8 + 4];
      uint4 v;
      v.x = f.h[0].x; v.y = f.h[0].y; v.z = f.h[1].x; v.w = f.h[1].y;
      *(uint4*)(wt + (size_t)(n0 + nl) * DIMD + k0 + c * 8) = v;
    }
  }
}

// ---------------------------------------------------------------------------
// qk_gemm: 128x128 tile, 512 threads = 8 waves (2 wm x 4 wn), wave = 64x32
//   (acc 4x2). Same LDS/staging as before but 2x waves/CU -> 16 waves/CU.
// ---------------------------------------------------------------------------
__global__ __launch_bounds__(512) void qk_gemm(const unsigned short* __restrict__ xb,
                                               const unsigned short* __restrict__ wtq,
                                               const unsigned short* __restrict__ wtk,
                                               const float* __restrict__ bias,
                                               unsigned short* __restrict__ qout,
                                               unsigned short* __restrict__ kout) {
  __shared__ __align__(16) unsigned short Als[128][68];
  __shared__ __align__(16) unsigned short Bls[128][68];
  const int mb = blockIdx.x, nb = blockIdx.y;
  const bool isQ = (nb < 4);
  const unsigned short* wt = isQ ? wtq : wtk;
  unsigned short* outp = isQ ? qout : kout;
  const int n0 = (nb & 3) * 128, m0 = mb * 128;
  const int tid = threadIdx.x;
  const int wave = tid >> 6, lane = tid & 63;
  const int quad = lane >> 4, l16 = lane & 15;
  const int wm = wave >> 2, wn = wave & 3;

  f32x4 acc[4][2];
#pragma unroll
  for (int a = 0; a < 4; a++)
#pragma unroll
    for (int c = 0; c < 2; c++) acc[a][c] = (f32x4){0.f, 0.f, 0.f, 0.f};

  for (int k0 = 0; k0 < DIMD; k0 += 64) {
    __syncthreads();
#pragma unroll
    for (int r = 0; r < 2; r++) {
      int idx = tid + r * 512;          // 0..1023 -> A
      int row = idx >> 3, c = idx & 7;
      st8(&Als[row][c * 8], *(const uint4*)(xb + (size_t)(m0 + row) * DIMD + k0 + c * 8));
      st8(&Bls[row][c * 8], *(const uint4*)(wt + (size_t)(n0 + row) * DIMD + k0 + c * 8));
    }
    __syncthreads();
#pragma unroll
    for (int ks = 0; ks < 2; ks++) {
      bf16x8 af[4], bfr[2];
#pragma unroll
      for (int t = 0; t < 4; t++)
        af[t] = ld_frag(&Als[wm * 64 + t * 16 + l16][quad * 8 + ks * 32]);
#pragma unroll
      for (int t = 0; t < 2; t++)
        bfr[t] = ld_frag(&Bls[wn * 32 + t * 16 + l16][quad * 8 + ks * 32]);
#pragma unroll
      for (int tm = 0; tm < 4; tm++)
#pragma unroll
        for (int tn = 0; tn < 2; tn++)
          acc[tm][tn] =
              __builtin_amdgcn_mfma_f32_16x16x32_bf16(af[tm], bfr[tn], acc[tm][tn], 0, 0, 0);
    }
  }
#pragma unroll
  for (int tm = 0; tm < 4; tm++) {
#pragma unroll
    for (int tn = 0; tn < 2; tn++) {
#pragma unroll
      for (int r = 0; r < 4; r++) {
        int row = m0 + wm * 64 + tm * 16 + quad * 4 + r;
        int gcol = n0 + wn * 32 + tn * 16 + l16;
        float v = acc[tm][tn][r];
        if (isQ) v = v * SCALE + bias[gcol];
        outp[(size_t)row * DIMD + gcol] = f2bf(v);
      }
    }
  }
}

// ---------------------------------------------------------------------------
// attn: O = sigmoid(Q K^T) V, register-P operand-swap.
//   1024 threads = 16 waves = 4 j-groups x 4 waves. BM=128 (wave: 2
//   i-subtiles of 16). Group g: j in [g*512, g*512+512), 8 tiles of 64.
//   LDS: K[4][64][68] + V[4][64][68] = 69.6 KB -> 2 blocks/CU = 32 waves/CU.
//   NOTE: no min-waves launch bound — R6 showed (1024,8)'s 64-VGPR cap
//   causes scratch spill (1.7 GB HBM). Natural allocation ~60 VGPR.
// ---------------------------------------------------------------------------
__global__ __launch_bounds__(1024) void attn(const unsigned short* __restrict__ qb,
                                             const unsigned short* __restrict__ kb,
                                             const unsigned short* __restrict__ xtf,
                                             float* __restrict__ out) {
  __shared__ __align__(16) char smem[69632];
  unsigned short* Kall = (unsigned short*)smem;    // [4][64][68]
  unsigned short* Vall = Kall + 4 * 64 * 68;       // [4][64][68]
  float* R0 = (float*)smem;                        // [128][66] combine region 0
  float* R1 = R0 + 128 * 66;                       // [128][66] combine region 1

  const int it = blockIdx.x, bh = blockIdx.y;
  const int b = bh >> 3, h = bh & 7;
  const int i0 = it * 128;
  const int tid = threadIdx.x;
  const int lane = tid & 63;
  const int grp = tid >> 8;          // j-group 0..3
  const int wv = (tid >> 6) & 3;     // wave within group
  const int gtid = tid & 255;
  const int quad = lane >> 4, l16 = lane & 15;

  // Q B-fragments for 2 i-subtiles
  bf16x8 qf[2][2];
  int irow[2];
#pragma unroll
  for (int s_ = 0; s_ < 2; s_++) {
    irow[s_] = i0 + wv * 32 + s_ * 16 + l16;
    const unsigned short* qp = qb + ((size_t)b * NN + irow[s_]) * DIMD + h * DKK + quad * 8;
    qf[s_][0] = *(const bf16x8*)qp;
    qf[s_][1] = *(const bf16x8*)(qp + 32);
  }

  f32x4 o[2][4];
#pragma unroll
  for (int s_ = 0; s_ < 2; s_++)
#pragma unroll
    for (int td = 0; td < 4; td++) o[s_][td] = (f32x4){0.f, 0.f, 0.f, 0.f};

  const unsigned short* kbase = kb + (size_t)b * NN * DIMD + h * DKK;
  const unsigned short* vbase = xtf + ((size_t)b * DIMD + h * DKK) * NN;
  unsigned short* Kg = Kall + grp * (64 * 68);
  unsigned short* Vg = Vall + grp * (64 * 68);
  const int jbase = grp * 512;

  for (int itr = 0; itr < 8; itr++) {
    const int j0 = jbase + itr * 64;
    __syncthreads();
#pragma unroll
    for (int r = 0; r < 2; r++) {
      int idx = gtid + r * 256;         // 0..511
      int row = idx >> 3, c = idx & 7;  // 64 rows x 8 chunks
      st8(&Kg[row * 68 + c * 8], *(const uint4*)(kbase + (size_t)(j0 + row) * DIMD + c * 8));
      st8(&Vg[row * 68 + c * 8], *(const uint4*)(vbase + (size_t)row * NN + j0 + c * 8));
    }
    __syncthreads();

#pragma unroll
    for (int t = 0; t < 4; t++) {
      bf16x8 kf0 = ld_frag(&Kg[(t * 16 + l16) * 68 + quad * 8]);
      bf16x8 kf1 = ld_frag(&Kg[(t * 16 + l16) * 68 + quad * 8 + 32]);
      f16x4 pf[2];
#pragma unroll
      for (int s_ = 0; s_ < 2; s_++) {
        f32x4 sv = (f32x4){0.f, 0.f, 0.f, 0.f};
        sv = __builtin_amdgcn_mfma_f32_16x16x32_bf16(kf0, qf[s_][0], sv, 0, 0, 0);
        sv = __builtin_amdgcn_mfma_f32_16x16x32_bf16(kf1, qf[s_][1], sv, 0, 0, 0);
        pf[s_] = sig_pack(sv);
      }
#pragma unroll
      for (int td = 0; td < 4; td++) {
        f16x4 vf = __builtin_bit_cast(
            f16x4, *(const u32x2*)&Vg[(td * 16 + l16) * 68 + t * 16 + quad * 4]);
        o[0][td] = __builtin_amdgcn_mfma_f32_16x16x16f16(vf, pf[0], o[0][td], 0, 0, 0);
        o[1][td] = __builtin_amdgcn_mfma_f32_16x16x16f16(vf, pf[1], o[1][td], 0, 0, 0);
      }
    }
  }

  // ---- combine 4 groups' partial O^T via LDS tree (stride 66, b64) ----
  __syncthreads();
  if (grp == 1 || grp == 3) {
    float* R = (grp == 1) ? R0 : R1;
#pragma unroll
    for (int s_ = 0; s_ < 2; s_++)
#pragma unroll
      for (int td = 0; td < 4; td++) {
        int base = (wv * 32 + s_ * 16 + l16) * 66 + td * 16 + quad * 4;
        *(f32x2*)&R[base] = (f32x2){o[s_][td][0], o[s_][td][1]};
        *(f32x2*)&R[base + 2] = (f32x2){o[s_][td][2], o[s_][td][3]};
      }
  }
  __syncthreads();
  if (grp == 0 || grp == 2) {
    float* R = (grp == 0) ? R0 : R1;
#pragma unroll
    for (int s_ = 0; s_ < 2; s_++)
#pragma unroll
      for (int td = 0; td < 4; td++) {
        int base = (wv * 32 + s_ * 16 + l16) * 66 + td * 16 + quad * 4;
        f32x2 a = *(const f32x2*)&R[base];
        f32x2 c = *(const f32x2*)&R[base + 2];
        o[s_][td][0] += a.x; o[s_][td][1] += a.y;
        o[s_][td][2] += c.x; o[s_][td][3] += c.y;
      }
  }
  __syncthreads();
  if (grp == 2) {
#pragma unroll
    for (int s_ = 0; s_ < 2; s_++)
#pragma unroll
      for (int td = 0; td < 4; td++) {
        int base = (wv * 32 + s_ * 16 + l16) * 66 + td * 16 + quad * 4;
        *(f32x2*)&R0[base] = (f32x2){o[s_][td][0], o[s_][td][1]};
        *(f32x2*)&R0[base + 2] = (f32x2){o[s_][td][2], o[s_][td][3]};
      }
  }
  __syncthreads();
  if (grp == 0) {
#pragma unroll
    for (int s_ = 0; s_ < 2; s_++) {
#pragma unroll
      for (int td = 0; td < 4; td++) {
        int base = (wv * 32 + s_ * 16 + l16) * 66 + td * 16 + quad * 4;
        f32x2 a = *(const f32x2*)&R0[base];
        f32x2 c = *(const f32x2*)&R0[base + 2];
        o[s_][td][0] += a.x; o[s_][td][1] += a.y;
        o[s_][td][2] += c.x; o[s_][td][3] += c.y;
        float* op = out + ((size_t)b * NN + irow[s_]) * DIMD + h * DKK + td * 16 + quad * 4;
        *(f32x4*)op = o[s_][td];
      }
    }
  }
}

// ---------------------------------------------------------------------------
extern "C" void kernel_launch(void* const* d_in, const int* in_sizes, int n_in,
                              void* d_out, int out_size, void* d_ws, size_t ws_size,
                              hipStream_t stream) {
  const float* x = (const float*)d_in[0];
  const float* Wq = (const float*)d_in[1];
  const float* Wk = (const float*)d_in[2];
  const float* bias = (const float*)d_in[3]; // [1,8,1,64] flat = 512
  float* out = (float*)d_out;

  unsigned short* ws = (unsigned short*)d_ws;
  unsigned short* xb = ws;                         // 4,194,304
  unsigned short* xtf = xb + (size_t)MTOT * DIMD;  // 4,194,304 (f16 bits)
  unsigned short* wtq = xtf + (size_t)MTOT * DIMD; // 262,144
  unsigned short* wtk = wtq + (size_t)DIMD * DIMD; // 262,144
  unsigned short* qb = wtk + (size_t)DIMD * DIMD;  // 4,194,304
  unsigned short* kb = qb + (size_t)MTOT * DIMD;   // 4,194,304

  prep<<<dim3(2432), 256, 0, stream>>>(x, Wq, Wk, xb, xtf, wtq, wtk);
  qk_gemm<<<dim3(64, 8), 512, 0, stream>>>(xb, wtq, wtk, bias, qb, kb);
  attn<<<dim3(16, 32), 1024, 0, stream>>>(qb, kb, xtf, out);
}

// Round 10
// 158.394 us; speedup vs baseline: 1.1075x; 1.1075x over previous
//
#include <hip/hip_runtime.h>
#include <hip/hip_bf16.h>
#include <stdint.h>

// Problem constants
#define BB 4
#define NN 2048
#define DIMD 512
#define HH 8
#define DKK 64
#define MTOT (BB * NN)          // 8192
constexpr float SCALE = 0.125f; // DK^-0.5

typedef __attribute__((ext_vector_type(4))) float f32x4;
typedef __attribute__((ext_vector_type(2))) float f32x2;
typedef __attribute__((ext_vector_type(8))) short bf16x8;   // 8 bf16 (4 VGPRs)
typedef __attribute__((ext_vector_type(4))) _Float16 f16x4; // 4 f16 (2 VGPRs)
typedef __attribute__((ext_vector_type(2))) __fp16 fp16v2;  // cvt_pkrtz result
typedef __attribute__((ext_vector_type(4))) __fp16 fp16v4;
typedef __attribute__((ext_vector_type(2))) unsigned int u32x2;

union pack8 { unsigned short s[8]; uint4 v; };
union fragu { u32x2 h[2]; bf16x8 v; };

__device__ __forceinline__ unsigned short f2bf(float f) {
  union { float f; uint32_t u; } v; v.f = f;
  uint32_t u = v.u;
  return (unsigned short)((u + 0x7FFFu + ((u >> 16) & 1u)) >> 16); // RNE
}

__device__ __forceinline__ unsigned short f2h(float f) {
  union { _Float16 h; unsigned short u; } c; c.h = (_Float16)f;
  return c.u;
}

// LDS helpers for stride-68 (8B-aligned) rows: explicit b64 ops
__device__ __forceinline__ bf16x8 ld_frag(const unsigned short* p) {
  fragu f;
  f.h[0] = *(const u32x2*)p;
  f.h[1] = *(const u32x2*)(p + 4);
  return f.v;
}
__device__ __forceinline__ void st8(unsigned short* p, uint4 v) {
  *(u32x2*)p = (u32x2){v.x, v.y};
  *(u32x2*)(p + 4) = (u32x2){v.z, v.w};
}

// sigmoid via e=exp(-|x|) (1 transcendental) + deg-3 minimax for 1/(1+e)-0.5
__device__ __forceinline__ f16x4 sig_pack(f32x4 sv) {
  float e0 = __expf(-__builtin_fabsf(sv[0]));
  float e1 = __expf(-__builtin_fabsf(sv[1]));
  float e2 = __expf(-__builtin_fabsf(sv[2]));
  float e3 = __expf(-__builtin_fabsf(sv[3]));
  const f32x2 c3 = {-0.22184f, -0.22184f};
  const f32x2 c2 = {0.66550f, 0.66550f};
  const f32x2 c1 = {-0.94280f, -0.94280f};
  const f32x2 c0 = {0.49826f, 0.49826f};
  f32x2 eA = {e0, e1}, eB = {e2, e3};
  f32x2 pA = __builtin_elementwise_fma(
      __builtin_elementwise_fma(__builtin_elementwise_fma(c3, eA, c2), eA, c1),
      eA, c0);
  f32x2 pB = __builtin_elementwise_fma(
      __builtin_elementwise_fma(__builtin_elementwise_fma(c3, eB, c2), eB, c1),
      eB, c0);
  float r0 = __builtin_copysignf(pA.x, sv[0]) + 0.5f;
  float r1 = __builtin_copysignf(pA.y, sv[1]) + 0.5f;
  float r2 = __builtin_copysignf(pB.x, sv[2]) + 0.5f;
  float r3 = __builtin_copysignf(pB.y, sv[3]) + 0.5f;
  fp16v2 lo = __builtin_amdgcn_cvt_pkrtz(r0, r1);
  fp16v2 hi = __builtin_amdgcn_cvt_pkrtz(r2, r3);
  fp16v4 p;
  p.x = lo.x; p.y = lo.y; p.z = hi.x; p.w = hi.y;
  return __builtin_bit_cast(f16x4, p);
}

// ---------------------------------------------------------------------------
// prep (fused):
//   blocks [0,2048):    xb bf16 [B*N][DIM] — streaming convert
//   blocks [2048,2304): xtf f16 [B][DIM][N] — thread = (d, 64 n) -> one 128B
//                       contiguous write (full-line), reads coalesced over d
//   blocks [2304,2432): Wq/Wk -> Wt bf16 [N][K] via stride-68 LDS tile
// ---------------------------------------------------------------------------
__global__ __launch_bounds__(256) void prep(const float* __restrict__ x,
                                            const float* __restrict__ wq,
                                            const float* __restrict__ wk,
                                            unsigned short* __restrict__ xb,
                                            unsigned short* __restrict__ xtf,
                                            unsigned short* __restrict__ wtq,
                                            unsigned short* __restrict__ wtk) {
  const int bx = blockIdx.x, tid = threadIdx.x;
  if (bx < 2048) {
    size_t base = ((size_t)bx * 256 + tid) * 8;
    float4 a = *(const float4*)(x + base);
    float4 b = *(const float4*)(x + base + 4);
    pack8 p;
    p.s[0] = f2bf(a.x); p.s[1] = f2bf(a.y); p.s[2] = f2bf(a.z); p.s[3] = f2bf(a.w);
    p.s[4] = f2bf(b.x); p.s[5] = f2bf(b.y); p.s[6] = f2bf(b.z); p.s[7] = f2bf(b.w);
    *(uint4*)(xb + base) = p.v;
  } else if (bx < 2304) {
    int q = bx - 2048;
    int b = q >> 6, r = q & 63;
    int dt = r >> 3, nt = r & 7;
    int d = dt * 64 + (tid & 63);
    int n0 = nt * 256 + (tid >> 6) * 64;
    const float* xp = x + ((size_t)b * NN + n0) * DIMD + d;
    unsigned short* dp = xtf + ((size_t)b * DIMD + d) * NN + n0;
#pragma unroll
    for (int g = 0; g < 8; g++) {
      pack8 pa;
#pragma unroll
      for (int k = 0; k < 8; k++) pa.s[k] = f2h(xp[(size_t)(g * 8 + k) * DIMD]);
      *(uint4*)(dp + g * 8) = pa.v;
    }
  } else {
    __shared__ __align__(16) unsigned short T[64][68];
    int q = bx - 2304;
    const float* w = (q >= 64) ? wk : wq;
    unsigned short* wt = (q >= 64) ? wtk : wtq;
    int r = q & 63;
    int kt = r >> 3, nt = r & 7;
    const int k0 = kt * 64, n0 = nt * 64;
#pragma unroll
    for (int rr = 0; rr < 16; rr++) {
      int idx = tid + rr * 256;
      int kl = idx >> 6, nl = idx & 63;
      T[nl][kl] = f2bf(w[(size_t)(k0 + kl) * DIMD + n0 + nl]);
    }
    __syncthreads();
#pragma unroll
    for (int rr = 0; rr < 2; rr++) {
      int idx = tid + rr * 256;
      int nl = idx >> 3, c = idx & 7;
      fragu f;
      f.h[0] = *(const u32x2*)&T[nl][c * 8];
      f.h[1] = *(const u32x2*)&T[nl][c * 8 + 4];
      uint4 v;
      v.x = f.h[0].x; v.y = f.h[0].y; v.z = f.h[1].x; v.w = f.h[1].y;
      *(uint4*)(wt + (size_t)(n0 + nl) * DIMD + k0 + c * 8) = v;
    }
  }
}

// ---------------------------------------------------------------------------
// qk_gemm: 128x128 tile, 512 threads = 8 waves (2 wm x 4 wn), wave = 64x32,
//   with register prefetch of the next A/B tile (overlaps the barrier drain).
// ---------------------------------------------------------------------------
__global__ __launch_bounds__(512, 4) void qk_gemm(const unsigned short* __restrict__ xb,
                                                  const unsigned short* __restrict__ wtq,
                                                  const unsigned short* __restrict__ wtk,
                                                  const float* __restrict__ bias,
                                                  unsigned short* __restrict__ qout,
                                                  unsigned short* __restrict__ kout) {
  __shared__ __align__(16) unsigned short Als[128][68];
  __shared__ __align__(16) unsigned short Bls[128][68];
  const int mb = blockIdx.x, nb = blockIdx.y;
  const bool isQ = (nb < 4);
  const unsigned short* wt = isQ ? wtq : wtk;
  unsigned short* outp = isQ ? qout : kout;
  const int n0 = (nb & 3) * 128, m0 = mb * 128;
  const int tid = threadIdx.x;
  const int wave = tid >> 6, lane = tid & 63;
  const int quad = lane >> 4, l16 = lane & 15;
  const int wm = wave >> 2, wn = wave & 3;

  f32x4 acc[4][2];
#pragma unroll
  for (int a = 0; a < 4; a++)
#pragma unroll
    for (int c = 0; c < 2; c++) acc[a][c] = (f32x4){0.f, 0.f, 0.f, 0.f};

  const int srow[2] = {tid >> 3, (tid + 512) >> 3};
  const int scol = (tid & 7) * 8;
  uint4 pa[2], pb[2];
#pragma unroll
  for (int r = 0; r < 2; r++) {
    pa[r] = *(const uint4*)(xb + (size_t)(m0 + srow[r]) * DIMD + scol);
    pb[r] = *(const uint4*)(wt + (size_t)(n0 + srow[r]) * DIMD + scol);
  }

  for (int k0 = 0; k0 < DIMD; k0 += 64) {
    __syncthreads();
#pragma unroll
    for (int r = 0; r < 2; r++) {
      st8(&Als[srow[r]][scol], pa[r]);
      st8(&Bls[srow[r]][scol], pb[r]);
    }
    __syncthreads();
    if (k0 + 64 < DIMD) {
#pragma unroll
      for (int r = 0; r < 2; r++) {
        pa[r] = *(const uint4*)(xb + (size_t)(m0 + srow[r]) * DIMD + k0 + 64 + scol);
        pb[r] = *(const uint4*)(wt + (size_t)(n0 + srow[r]) * DIMD + k0 + 64 + scol);
      }
    }
#pragma unroll
    for (int ks = 0; ks < 2; ks++) {
      bf16x8 af[4], bfr[2];
#pragma unroll
      for (int t = 0; t < 4; t++)
        af[t] = ld_frag(&Als[wm * 64 + t * 16 + l16][quad * 8 + ks * 32]);
#pragma unroll
      for (int t = 0; t < 2; t++)
        bfr[t] = ld_frag(&Bls[wn * 32 + t * 16 + l16][quad * 8 + ks * 32]);
#pragma unroll
      for (int tm = 0; tm < 4; tm++)
#pragma unroll
        for (int tn = 0; tn < 2; tn++)
          acc[tm][tn] =
              __builtin_amdgcn_mfma_f32_16x16x32_bf16(af[tm], bfr[tn], acc[tm][tn], 0, 0, 0);
    }
  }
#pragma unroll
  for (int tm = 0; tm < 4; tm++) {
#pragma unroll
    for (int tn = 0; tn < 2; tn++) {
#pragma unroll
      for (int r = 0; r < 4; r++) {
        int row = m0 + wm * 64 + tm * 16 + quad * 4 + r;
        int gcol = n0 + wn * 32 + tn * 16 + l16;
        float v = acc[tm][tn][r];
        if (isQ) v = v * SCALE + bias[gcol];
        outp[(size_t)row * DIMD + gcol] = f2bf(v);
      }
    }
  }
}

// ---------------------------------------------------------------------------
// attn: O = sigmoid(Q K^T) V, register-P operand-swap. R5 geometry:
//   512 threads = 2 j-groups x 4 waves, BM=128 (wave: 2 i-subtiles), 16 itrs
//   of j-tile 64, LDS 34.8 KB, stride-68 conflict-free. NEW: register
//   prefetch of next K/V tile (global loads in flight across the MFMA phase).
// ---------------------------------------------------------------------------
__global__ __launch_bounds__(512, 4) void attn(const unsigned short* __restrict__ qb,
                                               const unsigned short* __restrict__ kb,
                                               const unsigned short* __restrict__ xtf,
                                               float* __restrict__ out) {
  __shared__ __align__(16) char smem[34816];
  unsigned short* Kall = (unsigned short*)smem;    // [2][64][68]
  unsigned short* Vall = Kall + 2 * 64 * 68;       // [2][64][68]
  float* R0 = (float*)smem;                        // [128][66] combine (reused)

  const int it = blockIdx.x, bh = blockIdx.y;
  const int b = bh >> 3, h = bh & 7;
  const int i0 = it * 128;
  const int tid = threadIdx.x;
  const int lane = tid & 63;
  const int grp = tid >> 8;          // j-group 0/1
  const int wv = (tid >> 6) & 3;     // wave within group
  const int gtid = tid & 255;
  const int quad = lane >> 4, l16 = lane & 15;

  // Q B-fragments for 2 i-subtiles
  bf16x8 qf[2][2];
  int irow[2];
#pragma unroll
  for (int s_ = 0; s_ < 2; s_++) {
    irow[s_] = i0 + wv * 32 + s_ * 16 + l16;
    const unsigned short* qp = qb + ((size_t)b * NN + irow[s_]) * DIMD + h * DKK + quad * 8;
    qf[s_][0] = *(const bf16x8*)qp;
    qf[s_][1] = *(const bf16x8*)(qp + 32);
  }

  f32x4 o[2][4];
#pragma unroll
  for (int s_ = 0; s_ < 2; s_++)
#pragma unroll
    for (int td = 0; td < 4; td++) o[s_][td] = (f32x4){0.f, 0.f, 0.f, 0.f};

  const unsigned short* kbase = kb + (size_t)b * NN * DIMD + h * DKK;
  const unsigned short* vbase = xtf + ((size_t)b * DIMD + h * DKK) * NN;
  unsigned short* Kg = Kall + grp * (64 * 68);
  unsigned short* Vg = Vall + grp * (64 * 68);
  const int jbase = grp * 1024;

  const int trow[2] = {gtid >> 3, (gtid + 256) >> 3};
  const int tcol = (gtid & 7) * 8;
  uint4 pk[2], pv[2];
#pragma unroll
  for (int r = 0; r < 2; r++) {
    pk[r] = *(const uint4*)(kbase + (size_t)(jbase + trow[r]) * DIMD + tcol);
    pv[r] = *(const uint4*)(vbase + (size_t)trow[r] * NN + jbase + tcol);
  }

  for (int itr = 0; itr < 16; itr++) {
    __syncthreads();
#pragma unroll
    for (int r = 0; r < 2; r++) {
      st8(&Kg[trow[r] * 68 + tcol], pk[r]);
      st8(&Vg[trow[r] * 68 + tcol], pv[r]);
    }
    __syncthreads();
    if (itr < 15) {
      const int j0 = jbase + (itr + 1) * 64;
#pragma unroll
      for (int r = 0; r < 2; r++) {
        pk[r] = *(const uint4*)(kbase + (size_t)(j0 + trow[r]) * DIMD + tcol);
        pv[r] = *(const uint4*)(vbase + (size_t)trow[r] * NN + j0 + tcol);
      }
    }

#pragma unroll
    for (int t = 0; t < 4; t++) {
      bf16x8 kf0 = ld_frag(&Kg[(t * 16 + l16) * 68 + quad * 8]);
      bf16x8 kf1 = ld_frag(&Kg[(t * 16 + l16) * 68 + quad * 8 + 32]);
      f16x4 pf[2];
#pragma unroll
      for (int s_ = 0; s_ < 2; s_++) {
        f32x4 sv = (f32x4){0.f, 0.f, 0.f, 0.f};
        sv = __builtin_amdgcn_mfma_f32_16x16x32_bf16(kf0, qf[s_][0], sv, 0, 0, 0);
        sv = __builtin_amdgcn_mfma_f32_16x16x32_bf16(kf1, qf[s_][1], sv, 0, 0, 0);
        pf[s_] = sig_pack(sv);
      }
#pragma unroll
      for (int td = 0; td < 4; td++) {
        f16x4 vf = __builtin_bit_cast(
            f16x4, *(const u32x2*)&Vg[(td * 16 + l16) * 68 + t * 16 + quad * 4]);
        o[0][td] = __builtin_amdgcn_mfma_f32_16x16x16f16(vf, pf[0], o[0][td], 0, 0, 0);
        o[1][td] = __builtin_amdgcn_mfma_f32_16x16x16f16(vf, pf[1], o[1][td], 0, 0, 0);
      }
    }
  }

  // combine the two j-groups' partial O^T through LDS; group 0 stores.
  __syncthreads();
  if (grp == 1) {
#pragma unroll
    for (int s_ = 0; s_ < 2; s_++)
#pragma unroll
      for (int td = 0; td < 4; td++) {
        int base = (wv * 32 + s_ * 16 + l16) * 66 + td * 16 + quad * 4;
        *(f32x2*)&R0[base] = (f32x2){o[s_][td][0], o[s_][td][1]};
        *(f32x2*)&R0[base + 2] = (f32x2){o[s_][td][2], o[s_][td][3]};
      }
  }
  __syncthreads();
  if (grp == 0) {
#pragma unroll
    for (int s_ = 0; s_ < 2; s_++) {
#pragma unroll
      for (int td = 0; td < 4; td++) {
        int base = (wv * 32 + s_ * 16 + l16) * 66 + td * 16 + quad * 4;
        f32x2 a = *(const f32x2*)&R0[base];
        f32x2 c = *(const f32x2*)&R0[base + 2];
        o[s_][td][0] += a.x; o[s_][td][1] += a.y;
        o[s_][td][2] += c.x; o[s_][td][3] += c.y;
        float* op = out + ((size_t)b * NN + irow[s_]) * DIMD + h * DKK + td * 16 + quad * 4;
        *(f32x4*)op = o[s_][td];
      }
    }
  }
}

// ---------------------------------------------------------------------------
extern "C" void kernel_launch(void* const* d_in, const int* in_sizes, int n_in,
                              void* d_out, int out_size, void* d_ws, size_t ws_size,
                              hipStream_t stream) {
  const float* x = (const float*)d_in[0];
  const float* Wq = (const float*)d_in[1];
  const float* Wk = (const float*)d_in[2];
  const float* bias = (const float*)d_in[3]; // [1,8,1,64] flat = 512
  float* out = (float*)d_out;

  unsigned short* ws = (unsigned short*)d_ws;
  unsigned short* xb = ws;                         // 4,194,304
  unsigned short* xtf = xb + (size_t)MTOT * DIMD;  // 4,194,304 (f16 bits)
  unsigned short* wtq = xtf + (size_t)MTOT * DIMD; // 262,144
  unsigned short* wtk = wtq + (size_t)DIMD * DIMD; // 262,144
  unsigned short* qb = wtk + (size_t)DIMD * DIMD;  // 4,194,304
  unsigned short* kb = qb + (size_t)MTOT * DIMD;   // 4,194,304

  prep<<<dim3(2432), 256, 0, stream>>>(x, Wq, Wk, xb, xtf, wtq, wtk);
  qk_gemm<<<dim3(64, 8), 512, 0, stream>>>(xb, wtq, wtk, bias, qb, kb);
  attn<<<dim3(16, 32), 512, 0, stream>>>(qb, kb, xtf, out);
}